// Round 15
// baseline (93.316 us; speedup 1.0000x reference)
//
#include <hip/hip_runtime.h>

constexpr int D = 128;

typedef __attribute__((ext_vector_type(8))) short short8;   // 8 bf16 (4 VGPR)
typedef __attribute__((ext_vector_type(4))) float f32x4;    // MFMA accumulator

__device__ __forceinline__ unsigned short f2bf(float f) {   // RNE f32->bf16
    unsigned u = __float_as_uint(f);
    u += 0x7fffu + ((u >> 16) & 1u);
    return (unsigned short)(u >> 16);
}

// ---------------- K1: per-block histogram of high-byte buckets (+ Wf pack) ----------------
// hist[bucket * NBLK + blk] = #edges in block blk with (col>>8)==bucket
__global__ __launch_bounds__(256) void k_hist(const int* __restrict__ col,
                                              int* __restrict__ hist, int E, int NBLK, int NBUCK,
                                              const float* __restrict__ W,
                                              unsigned short* __restrict__ Wf) {
    __shared__ int lh[256];
    int tid = threadIdx.x, blk = blockIdx.x;
    lh[tid] = 0;
    __syncthreads();
    int e = blk * 256 + tid;
    if (e < E) atomicAdd(&lh[col[e] >> 8], 1);
    __syncthreads();
    if (tid < NBUCK) hist[tid * NBLK + blk] = lh[tid];

    if (blk < 64) {   // Wf pack: fragment-ordered bf16 W (16384 threads)
        int t2 = blk * 256 + tid;
        int j  = t2 & 7;
        int l  = (t2 >> 3) & 63;
        int g  = t2 >> 9;
        int kc = g >> 3, t = g & 7;
        int k  = kc * 32 + ((l >> 4) * 4) + (j & 3) + ((j >> 2) * 16);
        int c  = t * 16 + (l & 15);
        Wf[t2] = f2bf(W[k * D + c]);
    }
}

// ---------------- K2: per-block (1024 elems) exclusive scan of hist ----------------
__global__ __launch_bounds__(256) void k_scan1(const int* __restrict__ in,
                                               int* __restrict__ outp,
                                               int* __restrict__ bsum, int n) {
    int tid = threadIdx.x;
    int lane = tid & 63, wv = tid >> 6;
    int i0 = (blockIdx.x * 256 + tid) * 4;
    int4 v = {0, 0, 0, 0};
    if (i0 + 3 < n) {
        v = *(const int4*)(in + i0);
    } else {
        if (i0 < n)     v.x = in[i0];
        if (i0 + 1 < n) v.y = in[i0 + 1];
        if (i0 + 2 < n) v.z = in[i0 + 2];
        if (i0 + 3 < n) v.w = in[i0 + 3];
    }
    int tsum = v.x + v.y + v.z + v.w;
    int x = tsum;
    #pragma unroll
    for (int off = 1; off < 64; off <<= 1) {
        int t = __shfl_up(x, off);
        if (lane >= off) x += t;
    }
    __shared__ int ws[4];
    if (lane == 63) ws[wv] = x;
    __syncthreads();
    int woff = 0;
    #pragma unroll
    for (int w = 0; w < 3; ++w) if (w < wv) woff += ws[w];
    int ex = woff + x - tsum;
    if (i0 < n)     outp[i0]     = ex;
    if (i0 + 1 < n) outp[i0 + 1] = ex + v.x;
    if (i0 + 2 < n) outp[i0 + 2] = ex + v.x + v.y;
    if (i0 + 3 < n) outp[i0 + 3] = ex + v.x + v.y + v.z;
    if (tid == 255) bsum[blockIdx.x] = woff + x;
}

// ---------------- K3: single-block exclusive scan of <=1024 block sums (in place) ----------------
__global__ __launch_bounds__(256) void k_scan2(int* __restrict__ bsum, int nb) {
    int tid = threadIdx.x;
    int lane = tid & 63, wv = tid >> 6;
    int i0 = tid * 4;
    int v0 = 0, v1 = 0, v2 = 0, v3 = 0;
    if (i0 < nb)     v0 = bsum[i0];
    if (i0 + 1 < nb) v1 = bsum[i0 + 1];
    if (i0 + 2 < nb) v2 = bsum[i0 + 2];
    if (i0 + 3 < nb) v3 = bsum[i0 + 3];
    int tsum = v0 + v1 + v2 + v3;
    int x = tsum;
    #pragma unroll
    for (int off = 1; off < 64; off <<= 1) {
        int t = __shfl_up(x, off);
        if (lane >= off) x += t;
    }
    __shared__ int ws[4];
    if (lane == 63) ws[wv] = x;
    __syncthreads();
    int woff = 0;
    #pragma unroll
    for (int w = 0; w < 3; ++w) if (w < wv) woff += ws[w];
    int ex = woff + x - tsum;
    if (i0 < nb)     bsum[i0]     = ex;
    if (i0 + 1 < nb) bsum[i0 + 1] = ex + v0;
    if (i0 + 2 < nb) bsum[i0 + 2] = ex + v0 + v1;
    if (i0 + 3 < nb) bsum[i0 + 3] = ex + v0 + v1 + v2;
}

// ---------------- K4: hybrid — bucket scatter (LDS-ranked, no global atomics) || MFMA GEMM ----------------
// even b, b/2 < gemmBlocks -> GEMM 64-row tile b/2 ; otherwise scatter block (1 edge/thread)
__global__ __launch_bounds__(256) void k_scatter_gemm(
        const int* __restrict__ row, const int* __restrict__ col,
        const int* __restrict__ scanA, const int* __restrict__ bsum,
        int2* __restrict__ buf1, int E, int NBLK,
        int gemmBlocks,
        const float* __restrict__ seq, const unsigned short* __restrict__ Wf,
        unsigned short* __restrict__ y16, int n) {
    __shared__ int scnt[256];
    int b = (int)blockIdx.x;
    int half = b >> 1;
    bool isGemm = ((b & 1) == 0) && (half < gemmBlocks);

    if (!isGemm) {
        int pIdx = (b < 2 * gemmBlocks) ? half : (b - gemmBlocks);
        scnt[threadIdx.x] = 0;
        __syncthreads();
        int e = pIdx * 256 + threadIdx.x;
        if (e < E) {
            int c = col[e];
            int r = row[e];
            int bucket = c >> 8;
            int rank = atomicAdd(&scnt[bucket], 1);     // LDS returning atomic: fast
            int idx = bucket * NBLK + pIdx;
            int base = scanA[idx] + bsum[idx >> 10];
            buf1[base + rank] = make_int2(r, c);        // fire-and-forget store
        }
        return;
    }

    // ---- GEMM path: 64-row tile, 4 waves x 16 rows, N=128 (8 n-tiles), K=128 (4 chunks) ----
    int w  = threadIdx.x >> 6;
    int l  = threadIdx.x & 63;
    int lr = l & 15;
    int lg = l >> 4;

    int row0 = half * 64;
    int m = row0 + w * 16 + lr;
    if (m >= n) m = n - 1;
    const float* sp = seq + (size_t)m * D;

    f32x4 acc[8];
    #pragma unroll
    for (int t = 0; t < 8; ++t) acc[t] = (f32x4){0.f, 0.f, 0.f, 0.f};

    const short8* WfB = (const short8*)Wf;

    #pragma unroll
    for (int kc = 0; kc < 4; ++kc) {
        int kb = kc * 32 + lg * 4;
        float4 lo = *(const float4*)(sp + kb);
        float4 hi = *(const float4*)(sp + kb + 16);
        short8 a;
        a[0] = (short)f2bf(lo.x); a[1] = (short)f2bf(lo.y);
        a[2] = (short)f2bf(lo.z); a[3] = (short)f2bf(lo.w);
        a[4] = (short)f2bf(hi.x); a[5] = (short)f2bf(hi.y);
        a[6] = (short)f2bf(hi.z); a[7] = (short)f2bf(hi.w);
        #pragma unroll
        for (int t = 0; t < 8; ++t) {
            short8 bf = WfB[(kc * 8 + t) * 64 + l];
            acc[t] = __builtin_amdgcn_mfma_f32_16x16x32_bf16(a, bf, acc[t], 0, 0, 0);
        }
    }

    #pragma unroll
    for (int i = 0; i < 4; ++i) {
        int g = row0 + w * 16 + lg * 4 + i;
        if (g < n) {
            unsigned short* yp = y16 + (size_t)g * D + lr;
            #pragma unroll
            for (int t = 0; t < 8; ++t) yp[t * 16] = f2bf(acc[t][i]);
        }
    }
}

// ---------------- K5: exact CSR build per high-bucket — all atomics in LDS ----------------
// block hb owns nodes [hb*256, hb*256+256): counts, LDS scan, writes srow/gstart/deg/dinv
__global__ __launch_bounds__(256) void k_placeB(const int2* __restrict__ buf1,
                                                const int* __restrict__ scanA,
                                                const int* __restrict__ bsum,
                                                int* __restrict__ srow,
                                                int* __restrict__ gstart,
                                                int* __restrict__ deg,
                                                float* __restrict__ dinv,
                                                int E, int NBLK, int NBUCK, int n) {
    __shared__ int cnt[256], ns[256], cnt2[256], ws[4];
    int hb = blockIdx.x, tid = threadIdx.x;

    int i0 = hb * NBLK;
    int s0 = scanA[i0] + bsum[i0 >> 10];
    int s1 = E;
    if (hb + 1 < NBUCK) { int i1 = (hb + 1) * NBLK; s1 = scanA[i1] + bsum[i1 >> 10]; }

    cnt[tid] = 0; cnt2[tid] = 0;
    __syncthreads();
    for (int i = s0 + tid; i < s1; i += 256)
        atomicAdd(&cnt[buf1[i].y & 255], 1);
    __syncthreads();

    // exclusive scan of 256 counts
    int v = cnt[tid];
    int lane = tid & 63, wv = tid >> 6;
    int x = v;
    #pragma unroll
    for (int off = 1; off < 64; off <<= 1) {
        int t = __shfl_up(x, off);
        if (lane >= off) x += t;
    }
    if (lane == 63) ws[wv] = x;
    __syncthreads();
    int woff = 0;
    #pragma unroll
    for (int w = 0; w < 3; ++w) if (w < wv) woff += ws[w];
    int excl = woff + x - v;
    ns[tid] = s0 + excl;
    int gid = hb * 256 + tid;
    if (gid < n) {
        gstart[gid] = s0 + excl;
        deg[gid] = v;
        dinv[gid] = rsqrtf((float)(v + 1));
    }
    __syncthreads();

    for (int i = s0 + tid; i < s1; i += 256) {
        int2 rc = buf1[i];
        int lcl = rc.y & 255;
        int p = atomicAdd(&cnt2[lcl], 1);   // LDS returning atomic
        srow[ns[lcl] + p] = rc.x;
    }
}

// ---------------- K6: per-node gather-reduce + norm + bias + PReLU (CSR) ----------------
// out[c] = prelu( dc * ( y[c]*dc + sum_e y[r_e]*dinv[r_e] ) + b )
__global__ __launch_bounds__(256) void k_agg(
        const int* __restrict__ srow, const int* __restrict__ gstart,
        const int* __restrict__ deg, const float* __restrict__ dinv,
        const unsigned short* __restrict__ y16,
        const float* __restrict__ b, const float* __restrict__ pw,
        float* __restrict__ out, int n) {
    int wid = (blockIdx.x * 256 + threadIdx.x) >> 6;   // one wave per node
    if (wid >= n) return;
    int lane = threadIdx.x & 63;

    int cnt = deg[wid];
    int s = gstart[wid];
    float dc = dinv[wid];

    unsigned sv = *(const unsigned*)(y16 + (size_t)wid * D + 2 * lane);
    float ax0 = __uint_as_float(sv << 16) * dc;
    float ay0 = __uint_as_float(sv & 0xffff0000u) * dc;
    float ax1 = 0.f, ay1 = 0.f, ax2 = 0.f, ay2 = 0.f, ax3 = 0.f, ay3 = 0.f;
    float ax4 = 0.f, ay4 = 0.f, ax5 = 0.f, ay5 = 0.f, ax6 = 0.f, ay6 = 0.f;
    float ax7 = 0.f, ay7 = 0.f;

    for (int base = 0; base < cnt; base += 64) {
        int chunk = cnt - base; if (chunk > 64) chunk = 64;
        int my = (base + lane < cnt) ? srow[s + base + lane] : 0;
        int k = 0;
        for (; k + 7 < chunk; k += 8) {
            int r0 = __shfl(my, k);
            int r1 = __shfl(my, k + 1);
            int r2 = __shfl(my, k + 2);
            int r3 = __shfl(my, k + 3);
            int r4 = __shfl(my, k + 4);
            int r5 = __shfl(my, k + 5);
            int r6 = __shfl(my, k + 6);
            int r7 = __shfl(my, k + 7);
            float d0 = dinv[r0]; float d1 = dinv[r1]; float d2 = dinv[r2]; float d3 = dinv[r3];
            float d4 = dinv[r4]; float d5 = dinv[r5]; float d6 = dinv[r6]; float d7 = dinv[r7];
            unsigned v0 = *(const unsigned*)(y16 + (size_t)r0 * D + 2 * lane);
            unsigned v1 = *(const unsigned*)(y16 + (size_t)r1 * D + 2 * lane);
            unsigned v2 = *(const unsigned*)(y16 + (size_t)r2 * D + 2 * lane);
            unsigned v3 = *(const unsigned*)(y16 + (size_t)r3 * D + 2 * lane);
            unsigned v4 = *(const unsigned*)(y16 + (size_t)r4 * D + 2 * lane);
            unsigned v5 = *(const unsigned*)(y16 + (size_t)r5 * D + 2 * lane);
            unsigned v6 = *(const unsigned*)(y16 + (size_t)r6 * D + 2 * lane);
            unsigned v7 = *(const unsigned*)(y16 + (size_t)r7 * D + 2 * lane);
            ax0 = fmaf(__uint_as_float(v0 << 16), d0, ax0); ay0 = fmaf(__uint_as_float(v0 & 0xffff0000u), d0, ay0);
            ax1 = fmaf(__uint_as_float(v1 << 16), d1, ax1); ay1 = fmaf(__uint_as_float(v1 & 0xffff0000u), d1, ay1);
            ax2 = fmaf(__uint_as_float(v2 << 16), d2, ax2); ay2 = fmaf(__uint_as_float(v2 & 0xffff0000u), d2, ay2);
            ax3 = fmaf(__uint_as_float(v3 << 16), d3, ax3); ay3 = fmaf(__uint_as_float(v3 & 0xffff0000u), d3, ay3);
            ax4 = fmaf(__uint_as_float(v4 << 16), d4, ax4); ay4 = fmaf(__uint_as_float(v4 & 0xffff0000u), d4, ay4);
            ax5 = fmaf(__uint_as_float(v5 << 16), d5, ax5); ay5 = fmaf(__uint_as_float(v5 & 0xffff0000u), d5, ay5);
            ax6 = fmaf(__uint_as_float(v6 << 16), d6, ax6); ay6 = fmaf(__uint_as_float(v6 & 0xffff0000u), d6, ay6);
            ax7 = fmaf(__uint_as_float(v7 << 16), d7, ax7); ay7 = fmaf(__uint_as_float(v7 & 0xffff0000u), d7, ay7);
        }
        for (; k < chunk; ++k) {
            int r = __shfl(my, k);
            float dr = dinv[r];
            unsigned vv = *(const unsigned*)(y16 + (size_t)r * D + 2 * lane);
            ax0 = fmaf(__uint_as_float(vv << 16), dr, ax0);
            ay0 = fmaf(__uint_as_float(vv & 0xffff0000u), dr, ay0);
        }
    }

    float sx = ((ax0 + ax1) + (ax2 + ax3)) + ((ax4 + ax5) + (ax6 + ax7));
    float sy = ((ay0 + ay1) + (ay2 + ay3)) + ((ay4 + ay5) + (ay6 + ay7));

    float2 bb = *(const float2*)(b + 2 * lane);
    float p = pw[0];
    float vx = sx * dc + bb.x;
    float vy = sy * dc + bb.y;
    vx = vx > 0.f ? vx : p * vx;
    vy = vy > 0.f ? vy : p * vy;
    *(float2*)(out + (size_t)wid * D + 2 * lane) = make_float2(vx, vy);
}

extern "C" void kernel_launch(void* const* d_in, const int* in_sizes, int n_in,
                              void* d_out, int out_size, void* d_ws, size_t ws_size,
                              hipStream_t stream) {
    const float* seq = (const float*)d_in[0];
    const int*   ei  = (const int*)d_in[1];   // [2, E]: row = ei, col = ei + E
    const float* W   = (const float*)d_in[2];
    const float* b   = (const float*)d_in[3];
    const float* pw  = (const float*)d_in[4];
    int n = in_sizes[0] / D;
    int E = in_sizes[1] / 2;

    float* out = (float*)d_out;

    int NBLK  = (E + 255) / 256;    // 3125 scatter blocks
    int NBUCK = (n + 255) / 256;    // 196 high-byte buckets
    int tot   = NBUCK * NBLK;       // 612500 hist entries
    int GB    = (n + 63) / 64;      // 782 GEMM tiles

    // workspace layout (256B-aligned chunks): ~28 MB
    auto align = [](size_t x) { return (x + 255) & ~(size_t)255; };
    char* p = (char*)d_ws;
    unsigned short* y16 = (unsigned short*)p; p += align((size_t)n * D * sizeof(unsigned short));
    unsigned short* Wf  = (unsigned short*)p; p += align((size_t)D * D * sizeof(unsigned short));
    int2* buf1  = (int2*)p;  p += align((size_t)E * sizeof(int2));
    int*  hist  = (int*)p;   p += align((size_t)tot * sizeof(int));
    int*  scanA = (int*)p;   p += align((size_t)tot * sizeof(int));
    int*  bsum  = (int*)p;   p += align(1024 * sizeof(int));
    int*  srow  = (int*)p;   p += align((size_t)E * sizeof(int));
    int*  gstart= (int*)p;   p += align((size_t)n * sizeof(int));
    int*  deg   = (int*)p;   p += align((size_t)n * sizeof(int));
    float* dinv = (float*)p; p += align((size_t)n * sizeof(float));

    k_hist<<<NBLK, 256, 0, stream>>>(ei + E, hist, E, NBLK, NBUCK, W, Wf);

    int sb = (tot + 1023) / 1024;   // 599 scan blocks (<= 1024 for k_scan2)
    k_scan1<<<sb, 256, 0, stream>>>(hist, scanA, bsum, tot);
    k_scan2<<<1, 256, 0, stream>>>(bsum, sb);

    k_scatter_gemm<<<GB + NBLK, 256, 0, stream>>>(
        ei, ei + E, scanA, bsum, buf1, E, NBLK, GB, seq, Wf, y16, n);

    k_placeB<<<NBUCK, 256, 0, stream>>>(buf1, scanA, bsum, srow, gstart, deg, dinv,
                                        E, NBLK, NBUCK, n);

    k_agg<<<(unsigned)(((long long)n * 64 + 255) / 256), 256, 0, stream>>>(
        srow, gstart, deg, dinv, y16, b, pw, out, n);
}

// Round 16
// 91.683 us; speedup vs baseline: 1.0178x; 1.0178x over previous
//
#include <hip/hip_runtime.h>

constexpr int D = 128;

typedef __attribute__((ext_vector_type(8))) short short8;   // 8 bf16 (4 VGPR)
typedef __attribute__((ext_vector_type(4))) float f32x4;    // MFMA accumulator

__device__ __forceinline__ unsigned short f2bf(float f) {   // RNE f32->bf16
    unsigned u = __float_as_uint(f);
    u += 0x7fffu + ((u >> 16) & 1u);
    return (unsigned short)(u >> 16);
}

// ---------------- K1: per-block histogram of high-byte buckets (+ Wf pack) ----------------
// hist[bucket * NBLK + blk] = #edges in block blk with (col>>8)==bucket
__global__ __launch_bounds__(256) void k_hist(const int* __restrict__ col,
                                              int* __restrict__ hist, int E, int NBLK, int NBUCK,
                                              const float* __restrict__ W,
                                              unsigned short* __restrict__ Wf) {
    __shared__ int lh[256];
    int tid = threadIdx.x, blk = blockIdx.x;
    lh[tid] = 0;
    __syncthreads();
    int e = blk * 256 + tid;
    if (e < E) atomicAdd(&lh[col[e] >> 8], 1);
    __syncthreads();
    if (tid < NBUCK) hist[tid * NBLK + blk] = lh[tid];

    if (blk < 64) {   // Wf pack: fragment-ordered bf16 W (16384 threads)
        int t2 = blk * 256 + tid;
        int j  = t2 & 7;
        int l  = (t2 >> 3) & 63;
        int g  = t2 >> 9;
        int kc = g >> 3, t = g & 7;
        int k  = kc * 32 + ((l >> 4) * 4) + (j & 3) + ((j >> 2) * 16);
        int c  = t * 16 + (l & 15);
        Wf[t2] = f2bf(W[k * D + c]);
    }
}

// ---------------- K2: per-block (1024 elems) exclusive scan of hist ----------------
__global__ __launch_bounds__(256) void k_scan1(const int* __restrict__ in,
                                               int* __restrict__ outp,
                                               int* __restrict__ bsum, int n) {
    int tid = threadIdx.x;
    int lane = tid & 63, wv = tid >> 6;
    int i0 = (blockIdx.x * 256 + tid) * 4;
    int4 v = {0, 0, 0, 0};
    if (i0 + 3 < n) {
        v = *(const int4*)(in + i0);
    } else {
        if (i0 < n)     v.x = in[i0];
        if (i0 + 1 < n) v.y = in[i0 + 1];
        if (i0 + 2 < n) v.z = in[i0 + 2];
        if (i0 + 3 < n) v.w = in[i0 + 3];
    }
    int tsum = v.x + v.y + v.z + v.w;
    int x = tsum;
    #pragma unroll
    for (int off = 1; off < 64; off <<= 1) {
        int t = __shfl_up(x, off);
        if (lane >= off) x += t;
    }
    __shared__ int ws[4];
    if (lane == 63) ws[wv] = x;
    __syncthreads();
    int woff = 0;
    #pragma unroll
    for (int w = 0; w < 3; ++w) if (w < wv) woff += ws[w];
    int ex = woff + x - tsum;
    if (i0 < n)     outp[i0]     = ex;
    if (i0 + 1 < n) outp[i0 + 1] = ex + v.x;
    if (i0 + 2 < n) outp[i0 + 2] = ex + v.x + v.y;
    if (i0 + 3 < n) outp[i0 + 3] = ex + v.x + v.y + v.z;
    if (tid == 255) bsum[blockIdx.x] = woff + x;
}

// ---------------- K3: single-block exclusive scan of <=1024 block sums (in place) ----------------
__global__ __launch_bounds__(256) void k_scan2(int* __restrict__ bsum, int nb) {
    int tid = threadIdx.x;
    int lane = tid & 63, wv = tid >> 6;
    int i0 = tid * 4;
    int v0 = 0, v1 = 0, v2 = 0, v3 = 0;
    if (i0 < nb)     v0 = bsum[i0];
    if (i0 + 1 < nb) v1 = bsum[i0 + 1];
    if (i0 + 2 < nb) v2 = bsum[i0 + 2];
    if (i0 + 3 < nb) v3 = bsum[i0 + 3];
    int tsum = v0 + v1 + v2 + v3;
    int x = tsum;
    #pragma unroll
    for (int off = 1; off < 64; off <<= 1) {
        int t = __shfl_up(x, off);
        if (lane >= off) x += t;
    }
    __shared__ int ws[4];
    if (lane == 63) ws[wv] = x;
    __syncthreads();
    int woff = 0;
    #pragma unroll
    for (int w = 0; w < 3; ++w) if (w < wv) woff += ws[w];
    int ex = woff + x - tsum;
    if (i0 < nb)     bsum[i0]     = ex;
    if (i0 + 1 < nb) bsum[i0 + 1] = ex + v0;
    if (i0 + 2 < nb) bsum[i0 + 2] = ex + v0 + v1;
    if (i0 + 3 < nb) bsum[i0 + 3] = ex + v0 + v1 + v2;
}

// ---------------- K4: hybrid — bucket scatter (LDS-ranked, no global atomics) || MFMA GEMM ----------------
// even b, b/2 < gemmBlocks -> GEMM 64-row tile b/2 ; otherwise scatter block (1 edge/thread)
__global__ __launch_bounds__(256) void k_scatter_gemm(
        const int* __restrict__ row, const int* __restrict__ col,
        const int* __restrict__ scanA, const int* __restrict__ bsum,
        int2* __restrict__ buf1, int E, int NBLK,
        int gemmBlocks,
        const float* __restrict__ seq, const unsigned short* __restrict__ Wf,
        unsigned short* __restrict__ y16, int n) {
    __shared__ int scnt[256];
    int b = (int)blockIdx.x;
    int half = b >> 1;
    bool isGemm = ((b & 1) == 0) && (half < gemmBlocks);

    if (!isGemm) {
        int pIdx = (b < 2 * gemmBlocks) ? half : (b - gemmBlocks);
        scnt[threadIdx.x] = 0;
        __syncthreads();
        int e = pIdx * 256 + threadIdx.x;
        if (e < E) {
            int c = col[e];
            int r = row[e];
            int bucket = c >> 8;
            int rank = atomicAdd(&scnt[bucket], 1);     // LDS returning atomic: fast
            int idx = bucket * NBLK + pIdx;
            int base = scanA[idx] + bsum[idx >> 10];
            buf1[base + rank] = make_int2(r, c);        // fire-and-forget store
        }
        return;
    }

    // ---- GEMM path: 64-row tile, 4 waves x 16 rows, N=128 (8 n-tiles), K=128 (4 chunks) ----
    int w  = threadIdx.x >> 6;
    int l  = threadIdx.x & 63;
    int lr = l & 15;
    int lg = l >> 4;

    int row0 = half * 64;
    int m = row0 + w * 16 + lr;
    if (m >= n) m = n - 1;
    const float* sp = seq + (size_t)m * D;

    f32x4 acc[8];
    #pragma unroll
    for (int t = 0; t < 8; ++t) acc[t] = (f32x4){0.f, 0.f, 0.f, 0.f};

    const short8* WfB = (const short8*)Wf;

    #pragma unroll
    for (int kc = 0; kc < 4; ++kc) {
        int kb = kc * 32 + lg * 4;
        float4 lo = *(const float4*)(sp + kb);
        float4 hi = *(const float4*)(sp + kb + 16);
        short8 a;
        a[0] = (short)f2bf(lo.x); a[1] = (short)f2bf(lo.y);
        a[2] = (short)f2bf(lo.z); a[3] = (short)f2bf(lo.w);
        a[4] = (short)f2bf(hi.x); a[5] = (short)f2bf(hi.y);
        a[6] = (short)f2bf(hi.z); a[7] = (short)f2bf(hi.w);
        #pragma unroll
        for (int t = 0; t < 8; ++t) {
            short8 bf = WfB[(kc * 8 + t) * 64 + l];
            acc[t] = __builtin_amdgcn_mfma_f32_16x16x32_bf16(a, bf, acc[t], 0, 0, 0);
        }
    }

    #pragma unroll
    for (int i = 0; i < 4; ++i) {
        int g = row0 + w * 16 + lg * 4 + i;
        if (g < n) {
            unsigned short* yp = y16 + (size_t)g * D + lr;
            #pragma unroll
            for (int t = 0; t < 8; ++t) yp[t * 16] = f2bf(acc[t][i]);
        }
    }
}

// ---------------- K5: exact CSR build per high-bucket — all atomics in LDS ----------------
// block hb owns nodes [hb*256, hb*256+256): counts, LDS scan, writes srow/gstart/deg/dinv
__global__ __launch_bounds__(256) void k_placeB(const int2* __restrict__ buf1,
                                                const int* __restrict__ scanA,
                                                const int* __restrict__ bsum,
                                                int* __restrict__ srow,
                                                int* __restrict__ gstart,
                                                int* __restrict__ deg,
                                                float* __restrict__ dinv,
                                                int E, int NBLK, int NBUCK, int n) {
    __shared__ int cnt[256], ns[256], cnt2[256], ws[4];
    int hb = blockIdx.x, tid = threadIdx.x;

    int i0 = hb * NBLK;
    int s0 = scanA[i0] + bsum[i0 >> 10];
    int s1 = E;
    if (hb + 1 < NBUCK) { int i1 = (hb + 1) * NBLK; s1 = scanA[i1] + bsum[i1 >> 10]; }

    cnt[tid] = 0; cnt2[tid] = 0;
    __syncthreads();
    for (int i = s0 + tid; i < s1; i += 256)
        atomicAdd(&cnt[buf1[i].y & 255], 1);
    __syncthreads();

    // exclusive scan of 256 counts
    int v = cnt[tid];
    int lane = tid & 63, wv = tid >> 6;
    int x = v;
    #pragma unroll
    for (int off = 1; off < 64; off <<= 1) {
        int t = __shfl_up(x, off);
        if (lane >= off) x += t;
    }
    if (lane == 63) ws[wv] = x;
    __syncthreads();
    int woff = 0;
    #pragma unroll
    for (int w = 0; w < 3; ++w) if (w < wv) woff += ws[w];
    int excl = woff + x - v;
    ns[tid] = s0 + excl;
    int gid = hb * 256 + tid;
    if (gid < n) {
        gstart[gid] = s0 + excl;
        deg[gid] = v;
        dinv[gid] = rsqrtf((float)(v + 1));
    }
    __syncthreads();

    for (int i = s0 + tid; i < s1; i += 256) {
        int2 rc = buf1[i];
        int lcl = rc.y & 255;
        int p = atomicAdd(&cnt2[lcl], 1);   // LDS returning atomic
        srow[ns[lcl] + p] = rc.x;
    }
}

// ---------------- K6: per-node gather-reduce + norm + bias + PReLU (CSR) ----------------
// out[c] = prelu( dc * ( y[c]*dc + sum_e y[r_e]*dinv[r_e] ) + b )
// 16-deep PREDICATED gather groups: invalid slots read node 0 with weight 0 (exact).
__global__ __launch_bounds__(256) void k_agg(
        const int* __restrict__ srow, const int* __restrict__ gstart,
        const int* __restrict__ deg, const float* __restrict__ dinv,
        const unsigned short* __restrict__ y16,
        const float* __restrict__ b, const float* __restrict__ pw,
        float* __restrict__ out, int n) {
    int wid = (blockIdx.x * 256 + threadIdx.x) >> 6;   // one wave per node
    if (wid >= n) return;
    int lane = threadIdx.x & 63;

    int cnt = deg[wid];
    int s = gstart[wid];
    float dc = dinv[wid];

    unsigned sv = *(const unsigned*)(y16 + (size_t)wid * D + 2 * lane);
    float ax0 = __uint_as_float(sv << 16) * dc;
    float ay0 = __uint_as_float(sv & 0xffff0000u) * dc;
    float ax1 = 0.f, ay1 = 0.f, ax2 = 0.f, ay2 = 0.f, ax3 = 0.f, ay3 = 0.f;
    float ax4 = 0.f, ay4 = 0.f, ax5 = 0.f, ay5 = 0.f, ax6 = 0.f, ay6 = 0.f;
    float ax7 = 0.f, ay7 = 0.f;

    for (int base = 0; base < cnt; base += 64) {
        int chunk = cnt - base; if (chunk > 64) chunk = 64;
        int my = (base + lane < cnt) ? srow[s + base + lane] : 0;   // invalid lanes -> node 0
        for (int k = 0; k < chunk; k += 16) {
            // 16 predicated gathers in flight; weight 0 for k+j >= chunk (fma(x,0,a)==a)
            int r0  = __shfl(my, k);      int r1  = __shfl(my, k + 1);
            int r2  = __shfl(my, k + 2);  int r3  = __shfl(my, k + 3);
            int r4  = __shfl(my, k + 4);  int r5  = __shfl(my, k + 5);
            int r6  = __shfl(my, k + 6);  int r7  = __shfl(my, k + 7);
            int r8  = __shfl(my, k + 8);  int r9  = __shfl(my, k + 9);
            int r10 = __shfl(my, k + 10); int r11 = __shfl(my, k + 11);
            int r12 = __shfl(my, k + 12); int r13 = __shfl(my, k + 13);
            int r14 = __shfl(my, k + 14); int r15 = __shfl(my, k + 15);
            float d0  = (k      < chunk) ? dinv[r0]  : 0.f;
            float d1  = (k + 1  < chunk) ? dinv[r1]  : 0.f;
            float d2  = (k + 2  < chunk) ? dinv[r2]  : 0.f;
            float d3  = (k + 3  < chunk) ? dinv[r3]  : 0.f;
            float d4  = (k + 4  < chunk) ? dinv[r4]  : 0.f;
            float d5  = (k + 5  < chunk) ? dinv[r5]  : 0.f;
            float d6  = (k + 6  < chunk) ? dinv[r6]  : 0.f;
            float d7  = (k + 7  < chunk) ? dinv[r7]  : 0.f;
            float d8  = (k + 8  < chunk) ? dinv[r8]  : 0.f;
            float d9  = (k + 9  < chunk) ? dinv[r9]  : 0.f;
            float d10 = (k + 10 < chunk) ? dinv[r10] : 0.f;
            float d11 = (k + 11 < chunk) ? dinv[r11] : 0.f;
            float d12 = (k + 12 < chunk) ? dinv[r12] : 0.f;
            float d13 = (k + 13 < chunk) ? dinv[r13] : 0.f;
            float d14 = (k + 14 < chunk) ? dinv[r14] : 0.f;
            float d15 = (k + 15 < chunk) ? dinv[r15] : 0.f;
            unsigned v0  = *(const unsigned*)(y16 + (size_t)r0  * D + 2 * lane);
            unsigned v1  = *(const unsigned*)(y16 + (size_t)r1  * D + 2 * lane);
            unsigned v2  = *(const unsigned*)(y16 + (size_t)r2  * D + 2 * lane);
            unsigned v3  = *(const unsigned*)(y16 + (size_t)r3  * D + 2 * lane);
            unsigned v4  = *(const unsigned*)(y16 + (size_t)r4  * D + 2 * lane);
            unsigned v5  = *(const unsigned*)(y16 + (size_t)r5  * D + 2 * lane);
            unsigned v6  = *(const unsigned*)(y16 + (size_t)r6  * D + 2 * lane);
            unsigned v7  = *(const unsigned*)(y16 + (size_t)r7  * D + 2 * lane);
            unsigned v8  = *(const unsigned*)(y16 + (size_t)r8  * D + 2 * lane);
            unsigned v9  = *(const unsigned*)(y16 + (size_t)r9  * D + 2 * lane);
            unsigned v10 = *(const unsigned*)(y16 + (size_t)r10 * D + 2 * lane);
            unsigned v11 = *(const unsigned*)(y16 + (size_t)r11 * D + 2 * lane);
            unsigned v12 = *(const unsigned*)(y16 + (size_t)r12 * D + 2 * lane);
            unsigned v13 = *(const unsigned*)(y16 + (size_t)r13 * D + 2 * lane);
            unsigned v14 = *(const unsigned*)(y16 + (size_t)r14 * D + 2 * lane);
            unsigned v15 = *(const unsigned*)(y16 + (size_t)r15 * D + 2 * lane);
            ax0 = fmaf(__uint_as_float(v0  << 16), d0,  ax0); ay0 = fmaf(__uint_as_float(v0  & 0xffff0000u), d0,  ay0);
            ax1 = fmaf(__uint_as_float(v1  << 16), d1,  ax1); ay1 = fmaf(__uint_as_float(v1  & 0xffff0000u), d1,  ay1);
            ax2 = fmaf(__uint_as_float(v2  << 16), d2,  ax2); ay2 = fmaf(__uint_as_float(v2  & 0xffff0000u), d2,  ay2);
            ax3 = fmaf(__uint_as_float(v3  << 16), d3,  ax3); ay3 = fmaf(__uint_as_float(v3  & 0xffff0000u), d3,  ay3);
            ax4 = fmaf(__uint_as_float(v4  << 16), d4,  ax4); ay4 = fmaf(__uint_as_float(v4  & 0xffff0000u), d4,  ay4);
            ax5 = fmaf(__uint_as_float(v5  << 16), d5,  ax5); ay5 = fmaf(__uint_as_float(v5  & 0xffff0000u), d5,  ay5);
            ax6 = fmaf(__uint_as_float(v6  << 16), d6,  ax6); ay6 = fmaf(__uint_as_float(v6  & 0xffff0000u), d6,  ay6);
            ax7 = fmaf(__uint_as_float(v7  << 16), d7,  ax7); ay7 = fmaf(__uint_as_float(v7  & 0xffff0000u), d7,  ay7);
            ax0 = fmaf(__uint_as_float(v8  << 16), d8,  ax0); ay0 = fmaf(__uint_as_float(v8  & 0xffff0000u), d8,  ay0);
            ax1 = fmaf(__uint_as_float(v9  << 16), d9,  ax1); ay1 = fmaf(__uint_as_float(v9  & 0xffff0000u), d9,  ay1);
            ax2 = fmaf(__uint_as_float(v10 << 16), d10, ax2); ay2 = fmaf(__uint_as_float(v10 & 0xffff0000u), d10, ay2);
            ax3 = fmaf(__uint_as_float(v11 << 16), d11, ax3); ay3 = fmaf(__uint_as_float(v11 & 0xffff0000u), d11, ay3);
            ax4 = fmaf(__uint_as_float(v12 << 16), d12, ax4); ay4 = fmaf(__uint_as_float(v12 & 0xffff0000u), d12, ay4);
            ax5 = fmaf(__uint_as_float(v13 << 16), d13, ax5); ay5 = fmaf(__uint_as_float(v13 & 0xffff0000u), d13, ay5);
            ax6 = fmaf(__uint_as_float(v14 << 16), d14, ax6); ay6 = fmaf(__uint_as_float(v14 & 0xffff0000u), d14, ay6);
            ax7 = fmaf(__uint_as_float(v15 << 16), d15, ax7); ay7 = fmaf(__uint_as_float(v15 & 0xffff0000u), d15, ay7);
        }
    }

    float sx = ((ax0 + ax1) + (ax2 + ax3)) + ((ax4 + ax5) + (ax6 + ax7));
    float sy = ((ay0 + ay1) + (ay2 + ay3)) + ((ay4 + ay5) + (ay6 + ay7));

    float2 bb = *(const float2*)(b + 2 * lane);
    float p = pw[0];
    float vx = sx * dc + bb.x;
    float vy = sy * dc + bb.y;
    vx = vx > 0.f ? vx : p * vx;
    vy = vy > 0.f ? vy : p * vy;
    *(float2*)(out + (size_t)wid * D + 2 * lane) = make_float2(vx, vy);
}

extern "C" void kernel_launch(void* const* d_in, const int* in_sizes, int n_in,
                              void* d_out, int out_size, void* d_ws, size_t ws_size,
                              hipStream_t stream) {
    const float* seq = (const float*)d_in[0];
    const int*   ei  = (const int*)d_in[1];   // [2, E]: row = ei, col = ei + E
    const float* W   = (const float*)d_in[2];
    const float* b   = (const float*)d_in[3];
    const float* pw  = (const float*)d_in[4];
    int n = in_sizes[0] / D;
    int E = in_sizes[1] / 2;

    float* out = (float*)d_out;

    int NBLK  = (E + 255) / 256;    // 3125 scatter blocks
    int NBUCK = (n + 255) / 256;    // 196 high-byte buckets
    int tot   = NBUCK * NBLK;       // 612500 hist entries
    int GB    = (n + 63) / 64;      // 782 GEMM tiles

    // workspace layout (256B-aligned chunks): ~28 MB
    auto align = [](size_t x) { return (x + 255) & ~(size_t)255; };
    char* p = (char*)d_ws;
    unsigned short* y16 = (unsigned short*)p; p += align((size_t)n * D * sizeof(unsigned short));
    unsigned short* Wf  = (unsigned short*)p; p += align((size_t)D * D * sizeof(unsigned short));
    int2* buf1  = (int2*)p;  p += align((size_t)E * sizeof(int2));
    int*  hist  = (int*)p;   p += align((size_t)tot * sizeof(int));
    int*  scanA = (int*)p;   p += align((size_t)tot * sizeof(int));
    int*  bsum  = (int*)p;   p += align(1024 * sizeof(int));
    int*  srow  = (int*)p;   p += align((size_t)E * sizeof(int));
    int*  gstart= (int*)p;   p += align((size_t)n * sizeof(int));
    int*  deg   = (int*)p;   p += align((size_t)n * sizeof(int));
    float* dinv = (float*)p; p += align((size_t)n * sizeof(float));

    k_hist<<<NBLK, 256, 0, stream>>>(ei + E, hist, E, NBLK, NBUCK, W, Wf);

    int sb = (tot + 1023) / 1024;   // 599 scan blocks (<= 1024 for k_scan2)
    k_scan1<<<sb, 256, 0, stream>>>(hist, scanA, bsum, tot);
    k_scan2<<<1, 256, 0, stream>>>(bsum, sb);

    k_scatter_gemm<<<GB + NBLK, 256, 0, stream>>>(
        ei, ei + E, scanA, bsum, buf1, E, NBLK, GB, seq, Wf, y16, n);

    k_placeB<<<NBUCK, 256, 0, stream>>>(buf1, scanA, bsum, srow, gstart, deg, dinv,
                                        E, NBLK, NBUCK, n);

    k_agg<<<(unsigned)(((long long)n * 64 + 255) / 256), 256, 0, stream>>>(
        srow, gstart, deg, dinv, y16, b, pw, out, n);
}